// Round 5
// baseline (6980.491 us; speedup 1.0000x reference)
//
#include <hip/hip_runtime.h>
#include <math.h>

#define TT_ 128
#define DD 64
#define HH 256
#define BB 16      // batch rows per block (MFMA M-tile)
#define NBLK 64    // 1024/16
#define NTHR 1024  // 16 waves, 1 N-tile (16 cols) per wave

// f32 LDS stride (elements): 260*4B = 1040B (odd multiple of 16B)
#define SA 260
// bf16 plane strides (elements): 264*2B = 528B, 72*2B = 144B (odd multiples of 16B)
#define SB 264
#define SXB 72

typedef short bf16x8 __attribute__((ext_vector_type(8)));
typedef float f32x4 __attribute__((ext_vector_type(4)));
typedef unsigned int uint;
typedef unsigned short ushort;

// ---- fragment-linear packed weights (bf16 hi/lo pairs), written by prep ----
// frag elem (tile t, oct o): W[t*16 + l%16][o*32 + (l/16)*8 + j], hi at +0, lo at +512
__device__ ushort g_W1p[16 * 8 * 2 * 512];    // W1  (256x256): t*8192 + o*1024
__device__ ushort g_W2p[16 * 8 * 2 * 512];    // W2  (256x256)
__device__ ushort g_Wrzp[32 * 10 * 2 * 512];  // Whh rows 0..511 (o<8) | Wih rows 0..511 (o=8,9): t*10240 + o*1024
__device__ ushort g_Whnp[16 * 8 * 2 * 512];   // Whh rows 512..767
__device__ ushort g_Winp[16 * 2 * 512];       // Wih rows 512..767 (hi only): t*1024 + o*512

__device__ __forceinline__ ushort bf16_rne(float f) {
  uint u = __builtin_bit_cast(uint, f);
  return (ushort)((u + 0x7fffu + ((u >> 16) & 1u)) >> 16);
}
__device__ __forceinline__ float bf16_f32(ushort h) {
  uint u = ((uint)h) << 16;
  return __builtin_bit_cast(float, u);
}
// truncation split: hi+lo reproduces f to ~2^-17 rel
__device__ __forceinline__ void hl_split(float f, ushort& hi, ushort& lo) {
  const uint u = __builtin_bit_cast(uint, f);
  hi = (ushort)(u >> 16);
  const float fh = __builtin_bit_cast(float, u & 0xffff0000u);
  lo = (ushort)(__builtin_bit_cast(uint, f - fh) >> 16);
}

__global__ __launch_bounds__(256) void prep(
    const float* __restrict__ W1, const float* __restrict__ W2,
    const float* __restrict__ Wih, const float* __restrict__ Whh)
{
  const int s = blockIdx.x * 256 + threadIdx.x;
  const int S1 = 16 * 8 * 512;
  const int S2 = S1 + 16 * 8 * 512;
  const int S3 = S2 + 32 * 10 * 512;
  const int S4 = S3 + 16 * 8 * 512;
  const int S5 = S4 + 16 * 2 * 512;
  if (s >= S5) return;

  if (s < S2) {  // W1 / W2
    const int r = (s < S1) ? s : s - S1;
    const int t = r / (8 * 512);
    const int o = (r / 512) & 7;
    const int pos = r & 511;
    const int l = pos >> 3, j = pos & 7;
    const int n = t * 16 + (l & 15);
    const int k = o * 32 + (l >> 4) * 8 + j;
    const float w = (s < S1) ? W1[n * HH + k] : W2[n * HH + k];
    ushort hi = bf16_rne(w);
    ushort lo = bf16_rne(w - bf16_f32(hi));
    ushort* dst = (s < S1) ? g_W1p : g_W2p;
    dst[((t * 8 + o) * 2) * 512 + pos] = hi;
    dst[((t * 8 + o) * 2 + 1) * 512 + pos] = lo;
  } else if (s < S3) {  // Wrz
    const int r = s - S2;
    const int t = r / (10 * 512);
    const int o = (r / 512) % 10;
    const int pos = r & 511;
    const int l = pos >> 3, j = pos & 7;
    const int n = t * 16 + (l & 15);
    float w;
    if (o < 8) w = Whh[n * HH + o * 32 + (l >> 4) * 8 + j];
    else       w = Wih[n * DD + (o - 8) * 32 + (l >> 4) * 8 + j];
    ushort hi = bf16_rne(w);
    ushort lo = bf16_rne(w - bf16_f32(hi));
    g_Wrzp[((t * 10 + o) * 2) * 512 + pos] = hi;
    g_Wrzp[((t * 10 + o) * 2 + 1) * 512 + pos] = lo;
  } else if (s < S4) {  // Whn
    const int r = s - S3;
    const int t = r / (8 * 512);
    const int o = (r / 512) & 7;
    const int pos = r & 511;
    const int l = pos >> 3, j = pos & 7;
    const int n = 512 + t * 16 + (l & 15);
    const float w = Whh[n * HH + o * 32 + (l >> 4) * 8 + j];
    ushort hi = bf16_rne(w);
    ushort lo = bf16_rne(w - bf16_f32(hi));
    g_Whnp[((t * 8 + o) * 2) * 512 + pos] = hi;
    g_Whnp[((t * 8 + o) * 2 + 1) * 512 + pos] = lo;
  } else {  // Win (hi only)
    const int r = s - S4;
    const int t = r / (2 * 512);
    const int o = (r / 512) & 1;
    const int pos = r & 511;
    const int l = pos >> 3, j = pos & 7;
    const int n = 512 + t * 16 + (l & 15);
    const float w = Wih[n * DD + o * 32 + (l >> 4) * 8 + j];
    g_Winp[(t * 2 + o) * 512 + pos] = bf16_rne(w);
  }
}

#define MFMA(A, B, C) __builtin_amdgcn_mfma_f32_16x16x32_bf16((A), (B), (C), 0, 0, 0)

// LDS-only barrier: inter-wave comm is via LDS, wait lgkm only (keeps vmcnt loads in flight)
#define LBAR() asm volatile("s_waitcnt lgkmcnt(0)\ns_barrier" ::: "memory")

// 1 N-tile, K=256, 3-term split accumulation.
// Burst structure: issue ALL 16 weight loads (64 VGPR in flight), then ds_read+MFMA.
__device__ __forceinline__ f32x4 mm1(const ushort* __restrict__ Ahi,
                                     const ushort* __restrict__ Alo,
                                     const ushort* __restrict__ pack,
                                     int tile, int lane, f32x4 acc)
{
  const int aoff = (lane & 15) * SB + (lane >> 4) * 8;
  const ushort* wp = pack + (size_t)tile * 8192 + lane * 8;
  bf16x8 wh[8], wl[8];
#pragma unroll
  for (int o = 0; o < 8; ++o) {
    wh[o] = *(const bf16x8*)(wp + o * 1024);
    wl[o] = *(const bf16x8*)(wp + o * 1024 + 512);
  }
#pragma unroll
  for (int o = 0; o < 8; ++o) {
    const bf16x8 ah = *(const bf16x8*)(Ahi + aoff + o * 32);
    const bf16x8 al = *(const bf16x8*)(Alo + aoff + o * 32);
    acc = MFMA(ah, wh[o], acc);
    acc = MFMA(al, wh[o], acc);
    acc = MFMA(ah, wl[o], acc);
  }
  return acc;
}

// One Wrzp tile (r: tile=wv, z: tile=16+wv): K=256 h-part (3-term) + K=64 x-part (2-term)
__device__ __forceinline__ f32x4 mm_rzt(const ushort* __restrict__ Ahi,
                                        const ushort* __restrict__ Alo,
                                        const ushort* __restrict__ Xhi,
                                        const ushort* __restrict__ Xlo,
                                        int tile, int lane, f32x4 acc)
{
  const int aoff = (lane & 15) * SB + (lane >> 4) * 8;
  const int xoff = (lane & 15) * SXB + (lane >> 4) * 8;
  const ushort* p = g_Wrzp + (size_t)tile * 10240 + lane * 8;
  bf16x8 wh[8], wl[8], wx[2];
#pragma unroll
  for (int o = 0; o < 8; ++o) {
    wh[o] = *(const bf16x8*)(p + o * 1024);
    wl[o] = *(const bf16x8*)(p + o * 1024 + 512);
  }
#pragma unroll
  for (int o = 0; o < 2; ++o)
    wx[o] = *(const bf16x8*)(p + (8 + o) * 1024);
#pragma unroll
  for (int o = 0; o < 8; ++o) {
    const bf16x8 ah = *(const bf16x8*)(Ahi + aoff + o * 32);
    const bf16x8 al = *(const bf16x8*)(Alo + aoff + o * 32);
    acc = MFMA(ah, wh[o], acc);
    acc = MFMA(al, wh[o], acc);
    acc = MFMA(ah, wl[o], acc);
  }
#pragma unroll
  for (int o = 0; o < 2; ++o) {
    const bf16x8 xh = *(const bf16x8*)(Xhi + xoff + o * 32);
    const bf16x8 xl = *(const bf16x8*)(Xlo + xoff + o * 32);
    acc = MFMA(xh, wx[o], acc);
    acc = MFMA(xl, wx[o], acc);
  }
  return acc;
}

// GRU n-gate x-side: tile wv of Winp, K=64, hi-only weights, 2-term
__device__ __forceinline__ f32x4 mm_in(const ushort* __restrict__ Xhi,
                                       const ushort* __restrict__ Xlo,
                                       int wv, int lane, f32x4 acc)
{
  const int xoff = (lane & 15) * SXB + (lane >> 4) * 8;
  const ushort* pw = g_Winp + (size_t)wv * 1024 + lane * 8;
  bf16x8 w0 = *(const bf16x8*)(pw);
  bf16x8 w1 = *(const bf16x8*)(pw + 512);
  {
    const bf16x8 xh = *(const bf16x8*)(Xhi + xoff);
    const bf16x8 xl = *(const bf16x8*)(Xlo + xoff);
    acc = MFMA(xh, w0, acc);
    acc = MFMA(xl, w0, acc);
  }
  {
    const bf16x8 xh = *(const bf16x8*)(Xhi + xoff + 32);
    const bf16x8 xl = *(const bf16x8*)(Xlo + xoff + 32);
    acc = MFMA(xh, w1, acc);
    acc = MFMA(xl, w1, acc);
  }
  return acc;
}

__global__ __launch_bounds__(NTHR) void odegru_kernel(
    const float* __restrict__ x, const float* __restrict__ times,
    const float* __restrict__ mask,
    const float* __restrict__ b1, const float* __restrict__ b2,
    const float* __restrict__ bih, const float* __restrict__ bhh,
    float* __restrict__ out)
{
  // f32 state
  __shared__ __align__(16) float sAh[BB * SA];    // h (full f32 state)
  __shared__ __align__(16) float sAin[BB * SA];   // h_ode / RK stage input (f32)
  // bf16 hi/lo matmul planes
  __shared__ __align__(16) ushort sAhh[BB * SB], sAhl[BB * SB];
  __shared__ __align__(16) ushort sAinh[BB * SB], sAinl[BB * SB];
  __shared__ __align__(16) ushort sUh[BB * SB], sUl[BB * SB];
  __shared__ __align__(16) ushort sXh[BB * SXB], sXl[BB * SXB];
  __shared__ __align__(16) float sM[BB * TT_];    // mask rows for this block

  const int tid = threadIdx.x;
  const int lane = tid & 63;
  const int wv = tid >> 6;     // wave 0..15, owns output col-tile wv
  const int l15 = lane & 15;
  const int lq = lane >> 4;    // 0..3
  const int b0 = blockIdx.x * BB;

  const int c = wv * 16 + l15;       // this thread's output column
  const float b1c = b1[c];
  const float b2c = b2[c];
  const float brz_r = bih[c] + bhh[c];
  const float brz_z = bih[c + 256] + bhh[c + 256];
  const float bn_i = bih[c + 512];
  const float bn_h = bhh[c + 512];

  const f32x4 Z = {0.f, 0.f, 0.f, 0.f};

  // stage mask rows once (non-temporal: don't pollute L2)
  sM[tid] = __builtin_nontemporal_load(&mask[(size_t)b0 * TT_ + tid]);
  sM[tid + 1024] = __builtin_nontemporal_load(&mask[(size_t)b0 * TT_ + tid + 1024]);

  // feval: A-planes -> kv (per-thread: col c, batches lq*4+q)
  auto feval = [&](const ushort* Ahi, const ushort* Alo, f32x4& kv) {
    f32x4 a = mm1(Ahi, Alo, g_W1p, wv, lane, Z);
#pragma unroll
    for (int q = 0; q < 4; ++q) {
      const int b = lq * 4 + q;
      const float u = fmaxf(a[q] + b1c, 0.f);
      ushort hi, lo; hl_split(u, hi, lo);
      sUh[b * SB + c] = hi;
      sUl[b * SB + c] = lo;
    }
    LBAR();
    f32x4 p = mm1(sUh, sUl, g_W2p, wv, lane, Z);
    kv = p + b2c;
  };

  // sAin <- sAh + coef*v (f32) and refresh Ain planes
  auto wAin = [&](float coef, const f32x4& v) {
#pragma unroll
    for (int q = 0; q < 4; ++q) {
      const int b = lq * 4 + q;
      const float nv = sAh[b * SA + c] + coef * v[q];
      sAin[b * SA + c] = nv;
      ushort hi, lo; hl_split(nv, hi, lo);
      sAinh[b * SB + c] = hi;
      sAinl[b * SB + c] = lo;
    }
  };

  for (int t = 0; t < TT_; ++t) {
    // stage x[:, t, :] as hi/lo planes (non-temporal read)
    {
      const int b = tid >> 6, d = tid & 63;
      const float v = __builtin_nontemporal_load(&x[((size_t)(b0 + b) * TT_ + t) * DD + d]);
      ushort hi, lo; hl_split(v, hi, lo);
      sXh[b * SXB + d] = hi;
      sXl[b * SXB + d] = lo;
    }
    if (t == 0) {
      const int cc = tid & 255;
#pragma unroll
      for (int q = 0; q < 4; ++q) {
        const int b = (tid >> 8) * 4 + q;
        sAin[b * SA + cc] = 0.f;
        sAinh[b * SB + cc] = 0;
        sAinl[b * SB + cc] = 0;
      }
    }
    LBAR();

    if (t > 0) {
      const float dtv = times[t] - times[t - 1];
      f32x4 kv, ks;
      // k1 (reads h planes)
      feval(sAhh, sAhl, kv);
      ks = kv;
      wAin(0.5f * dtv, kv);
      LBAR();
      // k2
      feval(sAinh, sAinl, kv);
      ks += 2.0f * kv;
      wAin(0.5f * dtv, kv);
      LBAR();
      // k3
      feval(sAinh, sAinl, kv);
      ks += 2.0f * kv;
      wAin(dtv, kv);
      LBAR();
      // k4
      feval(sAinh, sAinl, kv);
      ks += kv;
      wAin(dtv * (1.0f / 6.0f), ks);  // sAin <- h_ode
      LBAR();
    }

    // ---- GRU: this wave computes r,z,hn,in for its 16 cols, all 16 batches ----
    {
      f32x4 ar = mm_rzt(sAinh, sAinl, sXh, sXl, wv, lane, Z);
      f32x4 az = mm_rzt(sAinh, sAinl, sXh, sXl, 16 + wv, lane, Z);
      f32x4 ahn = mm1(sAinh, sAinl, g_Whnp, wv, lane, Z);
      f32x4 ain = mm_in(sXh, sXl, wv, lane, Z);

#pragma unroll
      for (int q = 0; q < 4; ++q) {
        const int b = lq * 4 + q;
        const float gr = ar[q] + brz_r;
        const float gz = az[q] + brz_z;
        const float hn = ahn[q] + bn_h;
        const float gn = ain[q] + bn_i;
        const float hode = sAin[b * SA + c];
        const float rg = 1.f / (1.f + __expf(-gr));
        const float zg = 1.f / (1.f + __expf(-gz));
        const float ng = 1.f - 2.f / (__expf(2.f * (gn + rg * hn)) + 1.f);
        const float hnext = (1.f - zg) * ng + zg * hode;
        const float m = sM[b * TT_ + t];
        const float hnew = m * hnext + (1.f - m) * hode;
        // non-temporal store: keep the out-stream from evicting weights in L2
        __builtin_nontemporal_store(hnew, &out[((size_t)(b0 + b) * TT_ + t) * HH + c]);
        sAh[b * SA + c] = hnew;
        ushort hi, lo; hl_split(hnew, hi, lo);
        sAhh[b * SB + c] = hi;
        sAhl[b * SB + c] = lo;
      }
    }
    LBAR();
  }
}

extern "C" void kernel_launch(void* const* d_in, const int* in_sizes, int n_in,
                              void* d_out, int out_size, void* d_ws, size_t ws_size,
                              hipStream_t stream) {
  (void)in_sizes; (void)n_in; (void)d_ws; (void)ws_size; (void)out_size;
  const float* x     = (const float*)d_in[0];
  const float* times = (const float*)d_in[1];
  const float* mask  = (const float*)d_in[2];
  const float* W1    = (const float*)d_in[3];
  const float* b1    = (const float*)d_in[4];
  const float* W2    = (const float*)d_in[5];
  const float* b2    = (const float*)d_in[6];
  const float* Wih   = (const float*)d_in[7];
  const float* bih   = (const float*)d_in[8];
  const float* Whh   = (const float*)d_in[9];
  const float* bhh   = (const float*)d_in[10];
  float* out = (float*)d_out;

  hipLaunchKernelGGL(prep, dim3((376832 + 255) / 256), dim3(256), 0, stream,
                     W1, W2, Wih, Whh);
  hipLaunchKernelGGL(odegru_kernel, dim3(NBLK), dim3(NTHR), 0, stream,
                     x, times, mask, b1, b2, bih, bhh, out);
}

// Round 6
// 6629.257 us; speedup vs baseline: 1.0530x; 1.0530x over previous
//
#include <hip/hip_runtime.h>
#include <math.h>

#define TT_ 128
#define DD 64
#define HH 256
#define BB 16      // batch rows per block (MFMA M-tile)
#define NBLK 64    // 1024/16
#define NTHR 1024  // 16 waves, 1 N-tile (16 cols) per wave

// f32 LDS stride (elements): 260*4B = 1040B (odd multiple of 16B)
#define SA 260
// bf16 plane strides (elements): 264*2B = 528B, 72*2B = 144B (odd multiples of 16B)
#define SB 264
#define SXB 72

typedef short bf16x8 __attribute__((ext_vector_type(8)));
typedef float f32x4 __attribute__((ext_vector_type(4)));
typedef unsigned int uint;
typedef unsigned short ushort;

// ---- fragment-linear packed weights (bf16 hi/lo pairs), written by prep ----
// frag elem (tile t, oct o): W[t*16 + l%16][o*32 + (l/16)*8 + j], hi at +0, lo at +512
__device__ ushort g_W1p[16 * 8 * 2 * 512];    // W1  (256x256): t*8192 + o*1024
__device__ ushort g_W2p[16 * 8 * 2 * 512];    // W2  (256x256)
__device__ ushort g_Wrzp[32 * 10 * 2 * 512];  // Whh rows 0..511 (o<8) | Wih rows 0..511 (o=8,9): t*10240 + o*1024
__device__ ushort g_Whnp[16 * 8 * 2 * 512];   // Whh rows 512..767
__device__ ushort g_Winp[16 * 2 * 512];       // Wih rows 512..767 (hi only): t*1024 + o*512

__device__ __forceinline__ ushort bf16_rne(float f) {
  uint u = __builtin_bit_cast(uint, f);
  return (ushort)((u + 0x7fffu + ((u >> 16) & 1u)) >> 16);
}
__device__ __forceinline__ float bf16_f32(ushort h) {
  uint u = ((uint)h) << 16;
  return __builtin_bit_cast(float, u);
}
// truncation split: hi+lo reproduces f to ~2^-17 rel
__device__ __forceinline__ void hl_split(float f, ushort& hi, ushort& lo) {
  const uint u = __builtin_bit_cast(uint, f);
  hi = (ushort)(u >> 16);
  const float fh = __builtin_bit_cast(float, u & 0xffff0000u);
  lo = (ushort)(__builtin_bit_cast(uint, f - fh) >> 16);
}

__global__ __launch_bounds__(256) void prep(
    const float* __restrict__ W1, const float* __restrict__ W2,
    const float* __restrict__ Wih, const float* __restrict__ Whh)
{
  const int s = blockIdx.x * 256 + threadIdx.x;
  const int S1 = 16 * 8 * 512;
  const int S2 = S1 + 16 * 8 * 512;
  const int S3 = S2 + 32 * 10 * 512;
  const int S4 = S3 + 16 * 8 * 512;
  const int S5 = S4 + 16 * 2 * 512;
  if (s >= S5) return;

  if (s < S2) {  // W1 / W2
    const int r = (s < S1) ? s : s - S1;
    const int t = r / (8 * 512);
    const int o = (r / 512) & 7;
    const int pos = r & 511;
    const int l = pos >> 3, j = pos & 7;
    const int n = t * 16 + (l & 15);
    const int k = o * 32 + (l >> 4) * 8 + j;
    const float w = (s < S1) ? W1[n * HH + k] : W2[n * HH + k];
    ushort hi = bf16_rne(w);
    ushort lo = bf16_rne(w - bf16_f32(hi));
    ushort* dst = (s < S1) ? g_W1p : g_W2p;
    dst[((t * 8 + o) * 2) * 512 + pos] = hi;
    dst[((t * 8 + o) * 2 + 1) * 512 + pos] = lo;
  } else if (s < S3) {  // Wrz
    const int r = s - S2;
    const int t = r / (10 * 512);
    const int o = (r / 512) % 10;
    const int pos = r & 511;
    const int l = pos >> 3, j = pos & 7;
    const int n = t * 16 + (l & 15);
    float w;
    if (o < 8) w = Whh[n * HH + o * 32 + (l >> 4) * 8 + j];
    else       w = Wih[n * DD + (o - 8) * 32 + (l >> 4) * 8 + j];
    ushort hi = bf16_rne(w);
    ushort lo = bf16_rne(w - bf16_f32(hi));
    g_Wrzp[((t * 10 + o) * 2) * 512 + pos] = hi;
    g_Wrzp[((t * 10 + o) * 2 + 1) * 512 + pos] = lo;
  } else if (s < S4) {  // Whn
    const int r = s - S3;
    const int t = r / (8 * 512);
    const int o = (r / 512) & 7;
    const int pos = r & 511;
    const int l = pos >> 3, j = pos & 7;
    const int n = 512 + t * 16 + (l & 15);
    const float w = Whh[n * HH + o * 32 + (l >> 4) * 8 + j];
    ushort hi = bf16_rne(w);
    ushort lo = bf16_rne(w - bf16_f32(hi));
    g_Whnp[((t * 8 + o) * 2) * 512 + pos] = hi;
    g_Whnp[((t * 8 + o) * 2 + 1) * 512 + pos] = lo;
  } else {  // Win (hi only)
    const int r = s - S4;
    const int t = r / (2 * 512);
    const int o = (r / 512) & 1;
    const int pos = r & 511;
    const int l = pos >> 3, j = pos & 7;
    const int n = 512 + t * 16 + (l & 15);
    const float w = Wih[n * DD + o * 32 + (l >> 4) * 8 + j];
    g_Winp[(t * 2 + o) * 512 + pos] = bf16_rne(w);
  }
}

#define MFMA(A, B, C) __builtin_amdgcn_mfma_f32_16x16x32_bf16((A), (B), (C), 0, 0, 0)

// LDS-only barrier: inter-wave comm is via LDS, wait lgkm only (keeps vmcnt loads in flight)
#define LBAR() asm volatile("s_waitcnt lgkmcnt(0)\ns_barrier" ::: "memory")

// 1 N-tile, K=256, 3-term split accumulation.
// Burst: ALL 16 weight loads issued first (64 VGPR in flight), then ds_read+MFMA.
// Two accumulator chains (even/odd o) for MFMA ILP.
__device__ __forceinline__ f32x4 mm1(const ushort* __restrict__ Ahi,
                                     const ushort* __restrict__ Alo,
                                     const ushort* __restrict__ pack,
                                     int tile, int lane, f32x4 acc)
{
  const int aoff = (lane & 15) * SB + (lane >> 4) * 8;
  const ushort* wp = pack + (size_t)tile * 8192 + lane * 8;
  bf16x8 wh[8], wl[8];
#pragma unroll
  for (int o = 0; o < 8; ++o) {
    wh[o] = *(const bf16x8*)(wp + o * 1024);
    wl[o] = *(const bf16x8*)(wp + o * 1024 + 512);
  }
  f32x4 a0 = acc;
  f32x4 a1 = {0.f, 0.f, 0.f, 0.f};
#pragma unroll
  for (int o = 0; o < 8; ++o) {
    const bf16x8 ah = *(const bf16x8*)(Ahi + aoff + o * 32);
    const bf16x8 al = *(const bf16x8*)(Alo + aoff + o * 32);
    f32x4& ac = (o & 1) ? a1 : a0;
    ac = MFMA(ah, wh[o], ac);
    ac = MFMA(al, wh[o], ac);
    ac = MFMA(ah, wl[o], ac);
  }
  return a0 + a1;
}

// One Wrzp tile (r: tile=wv, z: tile=16+wv): K=256 h-part (3-term) + K=64 x-part (2-term)
__device__ __forceinline__ f32x4 mm_rzt(const ushort* __restrict__ Ahi,
                                        const ushort* __restrict__ Alo,
                                        const ushort* __restrict__ Xhi,
                                        const ushort* __restrict__ Xlo,
                                        int tile, int lane, f32x4 acc)
{
  const int aoff = (lane & 15) * SB + (lane >> 4) * 8;
  const int xoff = (lane & 15) * SXB + (lane >> 4) * 8;
  const ushort* p = g_Wrzp + (size_t)tile * 10240 + lane * 8;
  bf16x8 wh[8], wl[8], wx[2];
#pragma unroll
  for (int o = 0; o < 8; ++o) {
    wh[o] = *(const bf16x8*)(p + o * 1024);
    wl[o] = *(const bf16x8*)(p + o * 1024 + 512);
  }
#pragma unroll
  for (int o = 0; o < 2; ++o)
    wx[o] = *(const bf16x8*)(p + (8 + o) * 1024);
  f32x4 a0 = acc;
  f32x4 a1 = {0.f, 0.f, 0.f, 0.f};
#pragma unroll
  for (int o = 0; o < 8; ++o) {
    const bf16x8 ah = *(const bf16x8*)(Ahi + aoff + o * 32);
    const bf16x8 al = *(const bf16x8*)(Alo + aoff + o * 32);
    f32x4& ac = (o & 1) ? a1 : a0;
    ac = MFMA(ah, wh[o], ac);
    ac = MFMA(al, wh[o], ac);
    ac = MFMA(ah, wl[o], ac);
  }
#pragma unroll
  for (int o = 0; o < 2; ++o) {
    const bf16x8 xh = *(const bf16x8*)(Xhi + xoff + o * 32);
    const bf16x8 xl = *(const bf16x8*)(Xlo + xoff + o * 32);
    f32x4& ac = (o & 1) ? a1 : a0;
    ac = MFMA(xh, wx[o], ac);
    ac = MFMA(xl, wx[o], ac);
  }
  return a0 + a1;
}

// GRU n-gate x-side: tile wv of Winp, K=64, hi-only weights, 2-term
__device__ __forceinline__ f32x4 mm_in(const ushort* __restrict__ Xhi,
                                       const ushort* __restrict__ Xlo,
                                       int wv, int lane, f32x4 acc)
{
  const int xoff = (lane & 15) * SXB + (lane >> 4) * 8;
  const ushort* pw = g_Winp + (size_t)wv * 1024 + lane * 8;
  bf16x8 w0 = *(const bf16x8*)(pw);
  bf16x8 w1 = *(const bf16x8*)(pw + 512);
  {
    const bf16x8 xh = *(const bf16x8*)(Xhi + xoff);
    const bf16x8 xl = *(const bf16x8*)(Xlo + xoff);
    acc = MFMA(xh, w0, acc);
    acc = MFMA(xl, w0, acc);
  }
  {
    const bf16x8 xh = *(const bf16x8*)(Xhi + xoff + 32);
    const bf16x8 xl = *(const bf16x8*)(Xlo + xoff + 32);
    acc = MFMA(xh, w1, acc);
    acc = MFMA(xl, w1, acc);
  }
  return acc;
}

__global__ __launch_bounds__(NTHR, 4) void odegru_kernel(
    const float* __restrict__ x, const float* __restrict__ times,
    const float* __restrict__ mask,
    const float* __restrict__ b1, const float* __restrict__ b2,
    const float* __restrict__ bih, const float* __restrict__ bhh,
    float* __restrict__ out)
{
  // f32 state
  __shared__ __align__(16) float sAh[BB * SA];    // h (full f32 state)
  __shared__ __align__(16) float sAin[BB * SA];   // h_ode / RK stage input (f32)
  // bf16 hi/lo matmul planes
  __shared__ __align__(16) ushort sAhh[BB * SB], sAhl[BB * SB];
  __shared__ __align__(16) ushort sAinh[BB * SB], sAinl[BB * SB];
  __shared__ __align__(16) ushort sUh[BB * SB], sUl[BB * SB];
  __shared__ __align__(16) ushort sXh[BB * SXB], sXl[BB * SXB];
  __shared__ __align__(16) float sM[BB * TT_];    // mask rows for this block

  const int tid = threadIdx.x;
  const int lane = tid & 63;
  const int wv = tid >> 6;     // wave 0..15, owns output col-tile wv
  const int l15 = lane & 15;
  const int lq = lane >> 4;    // 0..3
  const int b0 = blockIdx.x * BB;

  const int c = wv * 16 + l15;       // this thread's output column
  const float b1c = b1[c];
  const float b2c = b2[c];
  const float brz_r = bih[c] + bhh[c];
  const float brz_z = bih[c + 256] + bhh[c + 256];
  const float bn_i = bih[c + 512];
  const float bn_h = bhh[c + 512];

  const f32x4 Z = {0.f, 0.f, 0.f, 0.f};

  // stage mask rows once
  sM[tid] = mask[(size_t)b0 * TT_ + tid];
  sM[tid + 1024] = mask[(size_t)b0 * TT_ + tid + 1024];

  // feval: A-planes -> kv (per-thread: col c, batches lq*4+q)
  auto feval = [&](const ushort* Ahi, const ushort* Alo, f32x4& kv) {
    f32x4 a = mm1(Ahi, Alo, g_W1p, wv, lane, Z);
#pragma unroll
    for (int q = 0; q < 4; ++q) {
      const int b = lq * 4 + q;
      const float u = fmaxf(a[q] + b1c, 0.f);
      ushort hi, lo; hl_split(u, hi, lo);
      sUh[b * SB + c] = hi;
      sUl[b * SB + c] = lo;
    }
    LBAR();
    f32x4 p = mm1(sUh, sUl, g_W2p, wv, lane, Z);
    kv = p + b2c;
  };

  // sAin <- sAh + coef*v (f32) and refresh Ain planes
  auto wAin = [&](float coef, const f32x4& v) {
#pragma unroll
    for (int q = 0; q < 4; ++q) {
      const int b = lq * 4 + q;
      const float nv = sAh[b * SA + c] + coef * v[q];
      sAin[b * SA + c] = nv;
      ushort hi, lo; hl_split(nv, hi, lo);
      sAinh[b * SB + c] = hi;
      sAinl[b * SB + c] = lo;
    }
  };

  for (int t = 0; t < TT_; ++t) {
    // stage x[:, t, :] as hi/lo planes
    {
      const int b = tid >> 6, d = tid & 63;
      const float v = x[((size_t)(b0 + b) * TT_ + t) * DD + d];
      ushort hi, lo; hl_split(v, hi, lo);
      sXh[b * SXB + d] = hi;
      sXl[b * SXB + d] = lo;
    }
    if (t == 0) {
      const int cc = tid & 255;
#pragma unroll
      for (int q = 0; q < 4; ++q) {
        const int b = (tid >> 8) * 4 + q;
        sAin[b * SA + cc] = 0.f;
        sAinh[b * SB + cc] = 0;
        sAinl[b * SB + cc] = 0;
      }
    }
    LBAR();

    if (t > 0) {
      const float dtv = times[t] - times[t - 1];
      f32x4 kv, ks;
      // k1 (reads h planes)
      feval(sAhh, sAhl, kv);
      ks = kv;
      wAin(0.5f * dtv, kv);
      LBAR();
      // k2
      feval(sAinh, sAinl, kv);
      ks += 2.0f * kv;
      wAin(0.5f * dtv, kv);
      LBAR();
      // k3
      feval(sAinh, sAinl, kv);
      ks += 2.0f * kv;
      wAin(dtv, kv);
      LBAR();
      // k4
      feval(sAinh, sAinl, kv);
      ks += kv;
      wAin(dtv * (1.0f / 6.0f), ks);  // sAin <- h_ode
      LBAR();
    }

    // ---- GRU: this wave computes r,z,hn,in for its 16 cols, all 16 batches ----
    {
      f32x4 ar = mm_rzt(sAinh, sAinl, sXh, sXl, wv, lane, Z);
      f32x4 az = mm_rzt(sAinh, sAinl, sXh, sXl, 16 + wv, lane, Z);
      f32x4 ahn = mm1(sAinh, sAinl, g_Whnp, wv, lane, Z);
      f32x4 ain = mm_in(sXh, sXl, wv, lane, Z);

#pragma unroll
      for (int q = 0; q < 4; ++q) {
        const int b = lq * 4 + q;
        const float gr = ar[q] + brz_r;
        const float gz = az[q] + brz_z;
        const float hn = ahn[q] + bn_h;
        const float gn = ain[q] + bn_i;
        const float hode = sAin[b * SA + c];
        const float rg = 1.f / (1.f + __expf(-gr));
        const float zg = 1.f / (1.f + __expf(-gz));
        const float ng = 1.f - 2.f / (__expf(2.f * (gn + rg * hn)) + 1.f);
        const float hnext = (1.f - zg) * ng + zg * hode;
        const float m = sM[b * TT_ + t];
        const float hnew = m * hnext + (1.f - m) * hode;
        // NT store: out is never re-read; don't let the stream allocate in L2
        __builtin_nontemporal_store(hnew, &out[((size_t)(b0 + b) * TT_ + t) * HH + c]);
        sAh[b * SA + c] = hnew;
        ushort hi, lo; hl_split(hnew, hi, lo);
        sAhh[b * SB + c] = hi;
        sAhl[b * SB + c] = lo;
      }
    }
    LBAR();
  }
}

extern "C" void kernel_launch(void* const* d_in, const int* in_sizes, int n_in,
                              void* d_out, int out_size, void* d_ws, size_t ws_size,
                              hipStream_t stream) {
  (void)in_sizes; (void)n_in; (void)d_ws; (void)ws_size; (void)out_size;
  const float* x     = (const float*)d_in[0];
  const float* times = (const float*)d_in[1];
  const float* mask  = (const float*)d_in[2];
  const float* W1    = (const float*)d_in[3];
  const float* b1    = (const float*)d_in[4];
  const float* W2    = (const float*)d_in[5];
  const float* b2    = (const float*)d_in[6];
  const float* Wih   = (const float*)d_in[7];
  const float* bih   = (const float*)d_in[8];
  const float* Whh   = (const float*)d_in[9];
  const float* bhh   = (const float*)d_in[10];
  float* out = (float*)d_out;

  hipLaunchKernelGGL(prep, dim3((376832 + 255) / 256), dim3(256), 0, stream,
                     W1, W2, Wih, Whh);
  hipLaunchKernelGGL(odegru_kernel, dim3(NBLK), dim3(NTHR), 0, stream,
                     x, times, mask, b1, b2, bih, bhh, out);
}